// Round 1
// baseline (1560.940 us; speedup 1.0000x reference)
//
#include <hip/hip_runtime.h>

#define D   256    // HIDDEN
#define B   1024   // NUM_GRAPHS
#define K2  512    // 2*D
#define G4  1024   // 4*D

// ---------------- weight prep: Wc = [W_ih[:,:D] + W_hh | W_ih[:,D:]], bc = b_ih + b_hh
__global__ void prep_weights(const float* __restrict__ W_ih, const float* __restrict__ W_hh,
                             const float* __restrict__ b_ih, const float* __restrict__ b_hh,
                             float* __restrict__ Wc, float* __restrict__ bc) {
    int idx = blockIdx.x * blockDim.x + threadIdx.x;
    if (idx < G4 * K2) {
        int j = idx >> 9;      // row (gate index), K2=512
        int k = idx & 511;     // col
        float w = W_ih[idx];
        if (k < D) w += W_hh[j * D + k];
        Wc[idx] = w;
    }
    if (idx < G4) bc[idx] = b_ih[idx] + b_hh[idx];
}

// ---------------- segment bounds via binary search (segment_ids sorted)
__global__ void seg_bounds(const int* __restrict__ seg, int* __restrict__ out, int N) {
    int b = blockIdx.x * blockDim.x + threadIdx.x;
    if (b > B) return;
    if (b == B) { out[B] = N; return; }
    int lo = 0, hi = N;
    while (lo < hi) {
        int mid = (lo + hi) >> 1;
        if (seg[mid] < b) lo = mid + 1; else hi = mid;
    }
    out[b] = lo;
}

// ---------------- fp32 GEMM: C[M,N] = A[M,K] * Bm[N,K]^T + bias[N]
// 64x64 tile, 16x16 threads, 4x4 microtile. M,N multiples of 64; K multiple of 16.
__global__ __launch_bounds__(256) void gemm_nt(const float* __restrict__ A,
                                               const float* __restrict__ Bm,
                                               const float* __restrict__ bias,
                                               float* __restrict__ C,
                                               int M, int N, int K) {
    __shared__ float As[16][68];
    __shared__ float Bs[16][68];
    int tid = threadIdx.x;
    int tx = tid & 15, ty = tid >> 4;
    int m0 = blockIdx.y << 6, n0 = blockIdx.x << 6;
    int lr = tid >> 2;            // 0..63 tile row
    int lk = (tid & 3) << 2;      // 0,4,8,12
    float acc[4][4] = {};
    for (int k0 = 0; k0 < K; k0 += 16) {
        float4 a4 = *(const float4*)(A  + (size_t)(m0 + lr) * K + k0 + lk);
        float4 b4 = *(const float4*)(Bm + (size_t)(n0 + lr) * K + k0 + lk);
        As[lk + 0][lr] = a4.x; As[lk + 1][lr] = a4.y; As[lk + 2][lr] = a4.z; As[lk + 3][lr] = a4.w;
        Bs[lk + 0][lr] = b4.x; Bs[lk + 1][lr] = b4.y; Bs[lk + 2][lr] = b4.z; Bs[lk + 3][lr] = b4.w;
        __syncthreads();
#pragma unroll
        for (int kk = 0; kk < 16; ++kk) {
            float a0 = As[kk][ty * 4 + 0], a1 = As[kk][ty * 4 + 1];
            float a2 = As[kk][ty * 4 + 2], a3 = As[kk][ty * 4 + 3];
            float b0 = Bs[kk][tx * 4 + 0], b1 = Bs[kk][tx * 4 + 1];
            float b2 = Bs[kk][tx * 4 + 2], b3 = Bs[kk][tx * 4 + 3];
            acc[0][0] += a0 * b0; acc[0][1] += a0 * b1; acc[0][2] += a0 * b2; acc[0][3] += a0 * b3;
            acc[1][0] += a1 * b0; acc[1][1] += a1 * b1; acc[1][2] += a1 * b2; acc[1][3] += a1 * b3;
            acc[2][0] += a2 * b0; acc[2][1] += a2 * b1; acc[2][2] += a2 * b2; acc[2][3] += a2 * b3;
            acc[3][0] += a3 * b0; acc[3][1] += a3 * b1; acc[3][2] += a3 * b2; acc[3][3] += a3 * b3;
        }
        __syncthreads();
    }
    int n = n0 + tx * 4;
    float bx = bias[n + 0], by = bias[n + 1], bz = bias[n + 2], bw = bias[n + 3];
#pragma unroll
    for (int i = 0; i < 4; ++i) {
        int m = m0 + ty * 4 + i;
        float4 o;
        o.x = acc[i][0] + bx; o.y = acc[i][1] + by; o.z = acc[i][2] + bz; o.w = acc[i][3] + bw;
        *(float4*)(C + (size_t)m * N + n) = o;
    }
}

// ---------------- LSTM elementwise epilogue: c,h update; h -> xcat[:, :D]
__global__ __launch_bounds__(256) void lstm_ep(const float* __restrict__ gates,
                                               float* __restrict__ c,
                                               float* __restrict__ xcat) {
    int idx = blockIdx.x * blockDim.x + threadIdx.x;   // 0 .. B*D
    int b = idx >> 8, j = idx & 255;
    const float* g = gates + (size_t)b * G4;
    float iv = g[j], fv = g[D + j], gv = g[2 * D + j], ov = g[3 * D + j];
    float si = 1.f / (1.f + expf(-iv));
    float sf = 1.f / (1.f + expf(-fv));
    float so = 1.f / (1.f + expf(-ov));
    float cn = sf * c[idx] + si * tanhf(gv);
    float hn = so * tanhf(cn);
    c[idx] = cn;
    xcat[(size_t)b * K2 + j] = hn;
}

// ---------------- fused attention: online segment softmax + weighted readout
// one block (256 threads) per segment; q = xcat[b, :D]; readout -> xcat[b, D:2D]
__global__ __launch_bounds__(256) void attn(const float* __restrict__ feat,
                                            const int* __restrict__ segs,
                                            float* __restrict__ xcat) {
    int b = blockIdx.x, tid = threadIdx.x;
    int s = segs[b], e = segs[b + 1];
    __shared__ float q_sh[D];
    __shared__ float w_sh[256];
    __shared__ float red[256];
    q_sh[tid] = xcat[(size_t)b * K2 + tid];
    __syncthreads();
    float m = -3.0e38f, l = 0.f, acc = 0.f;
    for (int base = s; base < e; base += 256) {
        int n = base + tid;
        float ev = -3.0e38f;
        if (n < e) {
            const float4* fr = (const float4*)(feat + (size_t)n * D);
            const float4* qf = (const float4*)q_sh;
            float d0 = 0.f, d1 = 0.f, d2 = 0.f, d3 = 0.f;
#pragma unroll 8
            for (int k = 0; k < D / 4; ++k) {
                float4 f4 = fr[k], q4 = qf[k];
                d0 += f4.x * q4.x; d1 += f4.y * q4.y;
                d2 += f4.z * q4.z; d3 += f4.w * q4.w;
            }
            ev = (d0 + d1) + (d2 + d3);
        }
        red[tid] = ev;
        __syncthreads();
#pragma unroll
        for (int off = 128; off > 0; off >>= 1) {
            if (tid < off) red[tid] = fmaxf(red[tid], red[tid + off]);
            __syncthreads();
        }
        float mnew = fmaxf(m, red[0]);
        __syncthreads();                       // everyone has read red[0]
        float w = (n < e) ? expf(ev - mnew) : 0.f;
        w_sh[tid] = w;
        red[tid] = w;
        __syncthreads();
#pragma unroll
        for (int off = 128; off > 0; off >>= 1) {
            if (tid < off) red[tid] += red[tid + off];
            __syncthreads();
        }
        float wsum = red[0];
        float scale = expf(m - mnew);          // first chunk: exp(-inf) = 0
        l = l * scale + wsum;
        acc *= scale;
        int jmax = min(256, e - base);
        for (int j = 0; j < jmax; ++j)
            acc = fmaf(w_sh[j], feat[(size_t)(base + j) * D + tid], acc);
        m = mnew;
        __syncthreads();                       // protect w_sh/red for next chunk
    }
    float r = (l > 0.f) ? acc / l : 0.f;
    xcat[(size_t)b * K2 + D + tid] = r;
}

extern "C" void kernel_launch(void* const* d_in, const int* in_sizes, int n_in,
                              void* d_out, int out_size, void* d_ws, size_t ws_size,
                              hipStream_t stream) {
    const float* feat   = (const float*)d_in[0];
    const int*   segids = (const int*)d_in[1];
    const float* W_ih   = (const float*)d_in[2];
    const float* W_hh   = (const float*)d_in[3];
    const float* b_ih   = (const float*)d_in[4];
    const float* b_hh   = (const float*)d_in[5];
    const float* fc_w   = (const float*)d_in[6];
    const float* fc_b   = (const float*)d_in[7];
    float* out = (float*)d_out;
    int N = in_sizes[1];   // N_NODES

    // workspace carve-up (fp32): ~9.5 MB total
    float* Wc    = (float*)d_ws;                 // [G4, K2]
    float* bc    = Wc   + (size_t)G4 * K2;       // [G4]
    float* xcat  = bc   + G4;                    // [B, K2]  = [h | readout] = q_star
    float* cbuf  = xcat + (size_t)B * K2;        // [B, D]
    float* gates = cbuf + (size_t)B * D;         // [B, G4]
    int*   segs  = (int*)(gates + (size_t)B * G4); // [B+1]

    hipMemsetAsync(xcat, 0, (size_t)B * K2 * sizeof(float), stream);
    hipMemsetAsync(cbuf, 0, (size_t)B * D  * sizeof(float), stream);

    hipLaunchKernelGGL(prep_weights, dim3((G4 * K2 + 255) / 256), dim3(256), 0, stream,
                       W_ih, W_hh, b_ih, b_hh, Wc, bc);
    hipLaunchKernelGGL(seg_bounds, dim3((B + 1 + 255) / 256), dim3(256), 0, stream,
                       segids, segs, N);

    for (int it = 0; it < 6; ++it) {
        hipLaunchKernelGGL(gemm_nt, dim3(G4 / 64, B / 64), dim3(256), 0, stream,
                           xcat, Wc, bc, gates, B, G4, K2);
        hipLaunchKernelGGL(lstm_ep, dim3(B), dim3(256), 0, stream, gates, cbuf, xcat);
        hipLaunchKernelGGL(attn, dim3(B), dim3(256), 0, stream, feat, segs, xcat);
    }
    hipLaunchKernelGGL(gemm_nt, dim3(D / 64, B / 64), dim3(256), 0, stream,
                       xcat, fc_w, fc_b, out, B, D, K2);
}

// Round 2
// 1300.473 us; speedup vs baseline: 1.2003x; 1.2003x over previous
//
#include <hip/hip_runtime.h>

#define D   256    // HIDDEN
#define B   1024   // NUM_GRAPHS
#define K2  512    // 2*D
#define G4  1024   // 4*D

// ---------------- weight prep: Wc = [W_ih[:,:D] + W_hh | W_ih[:,D:]], bc = b_ih + b_hh
__global__ void prep_weights(const float* __restrict__ W_ih, const float* __restrict__ W_hh,
                             const float* __restrict__ b_ih, const float* __restrict__ b_hh,
                             float* __restrict__ Wc, float* __restrict__ bc) {
    int idx = blockIdx.x * blockDim.x + threadIdx.x;
    if (idx < G4 * K2) {
        int j = idx >> 9;      // row (gate index), K2=512
        int k = idx & 511;     // col
        float w = W_ih[idx];
        if (k < D) w += W_hh[j * D + k];
        Wc[idx] = w;
    }
    if (idx < G4) bc[idx] = b_ih[idx] + b_hh[idx];
}

// ---------------- segment bounds via binary search (segment_ids sorted)
__global__ void seg_bounds(const int* __restrict__ seg, int* __restrict__ out, int N) {
    int b = blockIdx.x * blockDim.x + threadIdx.x;
    if (b > B) return;
    if (b == B) { out[B] = N; return; }
    int lo = 0, hi = N;
    while (lo < hi) {
        int mid = (lo + hi) >> 1;
        if (seg[mid] < b) lo = mid + 1; else hi = mid;
    }
    out[b] = lo;
}

// ---------------- fp32 GEMM: C[M,N] = A[M,K] * Bm[N,K]^T + bias[N]
// 64x64 tile, 16x16 threads, 4x4 microtile. M,N multiples of 64; K multiple of 16.
__global__ __launch_bounds__(256) void gemm_nt(const float* __restrict__ A,
                                               const float* __restrict__ Bm,
                                               const float* __restrict__ bias,
                                               float* __restrict__ C,
                                               int M, int N, int K) {
    __shared__ float As[16][68];
    __shared__ float Bs[16][68];
    int tid = threadIdx.x;
    int tx = tid & 15, ty = tid >> 4;
    int m0 = blockIdx.y << 6, n0 = blockIdx.x << 6;
    int lr = tid >> 2;            // 0..63 tile row
    int lk = (tid & 3) << 2;      // 0,4,8,12
    float acc[4][4] = {};
    for (int k0 = 0; k0 < K; k0 += 16) {
        float4 a4 = *(const float4*)(A  + (size_t)(m0 + lr) * K + k0 + lk);
        float4 b4 = *(const float4*)(Bm + (size_t)(n0 + lr) * K + k0 + lk);
        As[lk + 0][lr] = a4.x; As[lk + 1][lr] = a4.y; As[lk + 2][lr] = a4.z; As[lk + 3][lr] = a4.w;
        Bs[lk + 0][lr] = b4.x; Bs[lk + 1][lr] = b4.y; Bs[lk + 2][lr] = b4.z; Bs[lk + 3][lr] = b4.w;
        __syncthreads();
#pragma unroll
        for (int kk = 0; kk < 16; ++kk) {
            float a0 = As[kk][ty * 4 + 0], a1 = As[kk][ty * 4 + 1];
            float a2 = As[kk][ty * 4 + 2], a3 = As[kk][ty * 4 + 3];
            float b0 = Bs[kk][tx * 4 + 0], b1 = Bs[kk][tx * 4 + 1];
            float b2 = Bs[kk][tx * 4 + 2], b3 = Bs[kk][tx * 4 + 3];
            acc[0][0] += a0 * b0; acc[0][1] += a0 * b1; acc[0][2] += a0 * b2; acc[0][3] += a0 * b3;
            acc[1][0] += a1 * b0; acc[1][1] += a1 * b1; acc[1][2] += a1 * b2; acc[1][3] += a1 * b3;
            acc[2][0] += a2 * b0; acc[2][1] += a2 * b1; acc[2][2] += a2 * b2; acc[2][3] += a2 * b3;
            acc[3][0] += a3 * b0; acc[3][1] += a3 * b1; acc[3][2] += a3 * b2; acc[3][3] += a3 * b3;
        }
        __syncthreads();
    }
    int n = n0 + tx * 4;
    float bx = bias[n + 0], by = bias[n + 1], bz = bias[n + 2], bw = bias[n + 3];
#pragma unroll
    for (int i = 0; i < 4; ++i) {
        int m = m0 + ty * 4 + i;
        float4 o;
        o.x = acc[i][0] + bx; o.y = acc[i][1] + by; o.z = acc[i][2] + bz; o.w = acc[i][3] + bw;
        *(float4*)(C + (size_t)m * N + n) = o;
    }
}

// ---------------- LSTM elementwise epilogue: c,h update; h -> xcat[:, :D]
__global__ __launch_bounds__(256) void lstm_ep(const float* __restrict__ gates,
                                               float* __restrict__ c,
                                               float* __restrict__ xcat) {
    int idx = blockIdx.x * blockDim.x + threadIdx.x;   // 0 .. B*D
    int b = idx >> 8, j = idx & 255;
    const float* g = gates + (size_t)b * G4;
    float iv = g[j], fv = g[D + j], gv = g[2 * D + j], ov = g[3 * D + j];
    float si = 1.f / (1.f + expf(-iv));
    float sf = 1.f / (1.f + expf(-fv));
    float so = 1.f / (1.f + expf(-ov));
    float cn = sf * c[idx] + si * tanhf(gv);
    float hn = so * tanhf(cn);
    c[idx] = cn;
    xcat[(size_t)b * K2 + j] = hn;
}

// ---------------- fused attention: online segment softmax + weighted readout
// One block (256 threads = 4 waves) per segment. Chunk = 64 nodes held in
// registers: wave w owns rows w*16..w*16+15, lane l owns dims 4l..4l+3.
// feat is read from HBM exactly ONCE, fully coalesced (16B/lane).
__global__ __launch_bounds__(256) void attn(const float* __restrict__ feat,
                                            const int* __restrict__ segs,
                                            float* __restrict__ xcat) {
    int b = blockIdx.x, tid = threadIdx.x;
    int wave = tid >> 6, lane = tid & 63;
    int s = segs[b], e = segs[b + 1];

    __shared__ float e_sh[64];
    __shared__ float w_sh[64];
    __shared__ float acc_sh[4][D];

    // q fragment: dims 4*lane .. 4*lane+3 (same slice in every wave)
    float4 q4 = *(const float4*)(xcat + (size_t)b * K2 + lane * 4);

    float m = -3.0e38f, l = 0.f;
    float4 acc = make_float4(0.f, 0.f, 0.f, 0.f);

    for (int base = s; base < e; base += 64) {
        int cnt = min(64, e - base);
        // ---- load 16 rows per wave into registers (coalesced float4)
        float4 f[16];
#pragma unroll
        for (int t = 0; t < 16; ++t) {
            int n = base + wave * 16 + t;
            if (n < e) f[t] = *(const float4*)(feat + (size_t)n * D + lane * 4);
            else       f[t] = make_float4(0.f, 0.f, 0.f, 0.f);
        }
        // ---- dot products: wave butterfly reduce, lane t publishes row t
#pragma unroll
        for (int t = 0; t < 16; ++t) {
            float d = f[t].x * q4.x + f[t].y * q4.y + f[t].z * q4.z + f[t].w * q4.w;
#pragma unroll
            for (int off = 32; off > 0; off >>= 1) d += __shfl_xor(d, off, 64);
            if (lane == t) e_sh[wave * 16 + t] = d;
        }
        __syncthreads();
        // ---- running max over this chunk (block-uniform)
        float mc = m;
        for (int t = 0; t < cnt; ++t) mc = fmaxf(mc, e_sh[t]);
        if (tid < 64) w_sh[tid] = (tid < cnt) ? __expf(e_sh[tid] - mc) : 0.f;
        __syncthreads();
        float wsum = 0.f;
#pragma unroll 8
        for (int t = 0; t < 64; ++t) wsum += w_sh[t];
        float scale = __expf(m - mc);          // first chunk: exp(-huge)=0
        l = l * scale + wsum;
        m = mc;
        acc.x *= scale; acc.y *= scale; acc.z *= scale; acc.w *= scale;
        // ---- weighted accumulate from register-held rows
#pragma unroll
        for (int t = 0; t < 16; ++t) {
            float w = w_sh[wave * 16 + t];
            acc.x = fmaf(w, f[t].x, acc.x);
            acc.y = fmaf(w, f[t].y, acc.y);
            acc.z = fmaf(w, f[t].z, acc.z);
            acc.w = fmaf(w, f[t].w, acc.w);
        }
        __syncthreads();                       // e_sh/w_sh reused next chunk
    }
    // ---- cross-wave reduction of partial readouts
    acc_sh[wave][lane * 4 + 0] = acc.x;
    acc_sh[wave][lane * 4 + 1] = acc.y;
    acc_sh[wave][lane * 4 + 2] = acc.z;
    acc_sh[wave][lane * 4 + 3] = acc.w;
    __syncthreads();
    float r = acc_sh[0][tid] + acc_sh[1][tid] + acc_sh[2][tid] + acc_sh[3][tid];
    r = (l > 0.f) ? r / l : 0.f;
    xcat[(size_t)b * K2 + D + tid] = r;
}

extern "C" void kernel_launch(void* const* d_in, const int* in_sizes, int n_in,
                              void* d_out, int out_size, void* d_ws, size_t ws_size,
                              hipStream_t stream) {
    const float* feat   = (const float*)d_in[0];
    const int*   segids = (const int*)d_in[1];
    const float* W_ih   = (const float*)d_in[2];
    const float* W_hh   = (const float*)d_in[3];
    const float* b_ih   = (const float*)d_in[4];
    const float* b_hh   = (const float*)d_in[5];
    const float* fc_w   = (const float*)d_in[6];
    const float* fc_b   = (const float*)d_in[7];
    float* out = (float*)d_out;
    int N = in_sizes[1];   // N_NODES

    // workspace carve-up (fp32): ~9.5 MB total
    float* Wc    = (float*)d_ws;                 // [G4, K2]
    float* bc    = Wc   + (size_t)G4 * K2;       // [G4]
    float* xcat  = bc   + G4;                    // [B, K2]  = [h | readout] = q_star
    float* cbuf  = xcat + (size_t)B * K2;        // [B, D]
    float* gates = cbuf + (size_t)B * D;         // [B, G4]
    int*   segs  = (int*)(gates + (size_t)B * G4); // [B+1]

    hipMemsetAsync(xcat, 0, (size_t)B * K2 * sizeof(float), stream);
    hipMemsetAsync(cbuf, 0, (size_t)B * D  * sizeof(float), stream);

    hipLaunchKernelGGL(prep_weights, dim3((G4 * K2 + 255) / 256), dim3(256), 0, stream,
                       W_ih, W_hh, b_ih, b_hh, Wc, bc);
    hipLaunchKernelGGL(seg_bounds, dim3((B + 1 + 255) / 256), dim3(256), 0, stream,
                       segids, segs, N);

    for (int it = 0; it < 6; ++it) {
        hipLaunchKernelGGL(gemm_nt, dim3(G4 / 64, B / 64), dim3(256), 0, stream,
                           xcat, Wc, bc, gates, B, G4, K2);
        hipLaunchKernelGGL(lstm_ep, dim3(B), dim3(256), 0, stream, gates, cbuf, xcat);
        hipLaunchKernelGGL(attn, dim3(B), dim3(256), 0, stream, feat, segs, xcat);
    }
    hipLaunchKernelGGL(gemm_nt, dim3(D / 64, B / 64), dim3(256), 0, stream,
                       xcat, fc_w, fc_b, out, B, D, K2);
}

// Round 3
// 1231.402 us; speedup vs baseline: 1.2676x; 1.0561x over previous
//
#include <hip/hip_runtime.h>

#define D   256    // HIDDEN
#define B   1024   // NUM_GRAPHS
#define K2  512    // 2*D
#define G4  1024   // 4*D

// ---------------- weight prep: Wc = [W_ih[:,:D] + W_hh | W_ih[:,D:]], bc = b_ih + b_hh
__global__ void prep_weights(const float* __restrict__ W_ih, const float* __restrict__ W_hh,
                             const float* __restrict__ b_ih, const float* __restrict__ b_hh,
                             float* __restrict__ Wc, float* __restrict__ bc) {
    int idx = blockIdx.x * blockDim.x + threadIdx.x;
    if (idx < G4 * K2) {
        int j = idx >> 9;      // row (gate index), K2=512
        int k = idx & 511;     // col
        float w = W_ih[idx];
        if (k < D) w += W_hh[j * D + k];
        Wc[idx] = w;
    }
    if (idx < G4) bc[idx] = b_ih[idx] + b_hh[idx];
}

// ---------------- segment bounds via binary search (segment_ids sorted)
__global__ void seg_bounds(const int* __restrict__ seg, int* __restrict__ out, int N) {
    int b = blockIdx.x * blockDim.x + threadIdx.x;
    if (b > B) return;
    if (b == B) { out[B] = N; return; }
    int lo = 0, hi = N;
    while (lo < hi) {
        int mid = (lo + hi) >> 1;
        if (seg[mid] < b) lo = mid + 1; else hi = mid;
    }
    out[b] = lo;
}

// ---------------- fp32 GEMM: C[M,N] = A[M,K] * Bm[N,K]^T + bias[N]
__global__ __launch_bounds__(256) void gemm_nt(const float* __restrict__ A,
                                               const float* __restrict__ Bm,
                                               const float* __restrict__ bias,
                                               float* __restrict__ C,
                                               int M, int N, int K) {
    __shared__ float As[16][68];
    __shared__ float Bs[16][68];
    int tid = threadIdx.x;
    int tx = tid & 15, ty = tid >> 4;
    int m0 = blockIdx.y << 6, n0 = blockIdx.x << 6;
    int lr = tid >> 2;            // 0..63 tile row
    int lk = (tid & 3) << 2;      // 0,4,8,12
    float acc[4][4] = {};
    for (int k0 = 0; k0 < K; k0 += 16) {
        float4 a4 = *(const float4*)(A  + (size_t)(m0 + lr) * K + k0 + lk);
        float4 b4 = *(const float4*)(Bm + (size_t)(n0 + lr) * K + k0 + lk);
        As[lk + 0][lr] = a4.x; As[lk + 1][lr] = a4.y; As[lk + 2][lr] = a4.z; As[lk + 3][lr] = a4.w;
        Bs[lk + 0][lr] = b4.x; Bs[lk + 1][lr] = b4.y; Bs[lk + 2][lr] = b4.z; Bs[lk + 3][lr] = b4.w;
        __syncthreads();
#pragma unroll
        for (int kk = 0; kk < 16; ++kk) {
            float a0 = As[kk][ty * 4 + 0], a1 = As[kk][ty * 4 + 1];
            float a2 = As[kk][ty * 4 + 2], a3 = As[kk][ty * 4 + 3];
            float b0 = Bs[kk][tx * 4 + 0], b1 = Bs[kk][tx * 4 + 1];
            float b2 = Bs[kk][tx * 4 + 2], b3 = Bs[kk][tx * 4 + 3];
            acc[0][0] += a0 * b0; acc[0][1] += a0 * b1; acc[0][2] += a0 * b2; acc[0][3] += a0 * b3;
            acc[1][0] += a1 * b0; acc[1][1] += a1 * b1; acc[1][2] += a1 * b2; acc[1][3] += a1 * b3;
            acc[2][0] += a2 * b0; acc[2][1] += a2 * b1; acc[2][2] += a2 * b2; acc[2][3] += a2 * b3;
            acc[3][0] += a3 * b0; acc[3][1] += a3 * b1; acc[3][2] += a3 * b2; acc[3][3] += a3 * b3;
        }
        __syncthreads();
    }
    int n = n0 + tx * 4;
    float bx = bias[n + 0], by = bias[n + 1], bz = bias[n + 2], bw = bias[n + 3];
#pragma unroll
    for (int i = 0; i < 4; ++i) {
        int m = m0 + ty * 4 + i;
        float4 o;
        o.x = acc[i][0] + bx; o.y = acc[i][1] + by; o.z = acc[i][2] + bz; o.w = acc[i][3] + bw;
        *(float4*)(C + (size_t)m * N + n) = o;
    }
}

// ---------------- LSTM elementwise epilogue: c,h update; h -> xcat[:, :D]
__global__ __launch_bounds__(256) void lstm_ep(const float* __restrict__ gates,
                                               float* __restrict__ c,
                                               float* __restrict__ xcat) {
    int idx = blockIdx.x * blockDim.x + threadIdx.x;   // 0 .. B*D
    int b = idx >> 8, j = idx & 255;
    const float* g = gates + (size_t)b * G4;
    float iv = g[j], fv = g[D + j], gv = g[2 * D + j], ov = g[3 * D + j];
    float si = 1.f / (1.f + expf(-iv));
    float sf = 1.f / (1.f + expf(-fv));
    float so = 1.f / (1.f + expf(-ov));
    float cn = sf * c[idx] + si * tanhf(gv);
    float hn = so * tanhf(cn);
    c[idx] = cn;
    xcat[(size_t)b * K2 + j] = hn;
}

// ---------------- fused attention v2: register double-buffer + shuffle softmax
// One block (256 thr = 4 waves) per segment. 64-node chunk in registers:
// wave w owns rows w*16..w*16+15, lane l owns dims 4l..4l+3.
// Next chunk's loads are issued BEFORE this chunk's softmax/accumulate, so
// HBM stays busy across the (single) per-chunk barrier.
struct AttnState {
    float m, l;
    float4 acc;
};

__device__ __forceinline__ void attn_load(const float* __restrict__ feat,
                                          float4 (&g)[16], int base, int e,
                                          int wave, int lane) {
#pragma unroll
    for (int t = 0; t < 16; ++t) {
        int n = base + wave * 16 + t;
        if (n < e) g[t] = *(const float4*)(feat + (size_t)n * D + lane * 4);
        else       g[t] = make_float4(0.f, 0.f, 0.f, 0.f);
    }
}

__device__ __forceinline__ void attn_body(const float* __restrict__ feat,
                                          float4 (&f)[16], float4 (&g)[16],
                                          float (&e_sh)[64],
                                          int base, int e, int wave, int lane,
                                          const float4& q4, AttnState& st) {
    // ---- dots for the 16 rows this wave owns (f holds chunk data)
    float dsave = 0.f;
#pragma unroll
    for (int t = 0; t < 16; ++t) {
        float d = f[t].x * q4.x + f[t].y * q4.y + f[t].z * q4.z + f[t].w * q4.w;
#pragma unroll
        for (int off = 32; off > 0; off >>= 1) d += __shfl_xor(d, off, 64);
        if (lane == t) dsave = d;      // lane t keeps row (wave*16+t)'s dot
    }
    // ---- prefetch next chunk while dots/softmax proceed
    attn_load(feat, g, base + 64, e, wave, lane);
    if (lane < 16) e_sh[wave * 16 + lane] = dsave;
    __syncthreads();
    // ---- parallel softmax over the 64 chunk values: lane l owns value l
    float ev = (base + lane < e) ? e_sh[lane] : -3.0e38f;
    float cmax = ev;
#pragma unroll
    for (int off = 32; off > 0; off >>= 1) cmax = fmaxf(cmax, __shfl_xor(cmax, off, 64));
    float mc = fmaxf(st.m, cmax);
    float wl = __expf(ev - mc);        // invalid lanes: exp(-3e38 - mc) = 0
    float wsum = wl;
#pragma unroll
    for (int off = 32; off > 0; off >>= 1) wsum += __shfl_xor(wsum, off, 64);
    float scale = __expf(st.m - mc);   // first chunk: exp(-huge) = 0
    st.l = st.l * scale + wsum;
    st.m = mc;
    st.acc.x *= scale; st.acc.y *= scale; st.acc.z *= scale; st.acc.w *= scale;
    // ---- weighted accumulate from register-held rows
#pragma unroll
    for (int t = 0; t < 16; ++t) {
        float w = __shfl(wl, wave * 16 + t, 64);
        st.acc.x = fmaf(w, f[t].x, st.acc.x);
        st.acc.y = fmaf(w, f[t].y, st.acc.y);
        st.acc.z = fmaf(w, f[t].z, st.acc.z);
        st.acc.w = fmaf(w, f[t].w, st.acc.w);
    }
}

__global__ __launch_bounds__(256) void attn(const float* __restrict__ feat,
                                            const int* __restrict__ segs,
                                            float* __restrict__ xcat) {
    int b = blockIdx.x, tid = threadIdx.x;
    int wave = tid >> 6, lane = tid & 63;
    int s = segs[b], e = segs[b + 1];

    __shared__ float e_sh0[64];
    __shared__ float e_sh1[64];
    __shared__ float acc_sh[4][D];

    float4 q4 = *(const float4*)(xcat + (size_t)b * K2 + lane * 4);

    AttnState st;
    st.m = -3.0e38f; st.l = 0.f;
    st.acc = make_float4(0.f, 0.f, 0.f, 0.f);

    float4 fa[16], fb[16];
    if (s < e) {
        attn_load(feat, fa, s, e, wave, lane);
        int base = s;
        for (;;) {
            attn_body(feat, fa, fb, e_sh0, base, e, wave, lane, q4, st);
            base += 64; if (base >= e) break;
            attn_body(feat, fb, fa, e_sh1, base, e, wave, lane, q4, st);
            base += 64; if (base >= e) break;
        }
    }
    // ---- cross-wave reduction of partial readouts
    acc_sh[wave][lane * 4 + 0] = st.acc.x;
    acc_sh[wave][lane * 4 + 1] = st.acc.y;
    acc_sh[wave][lane * 4 + 2] = st.acc.z;
    acc_sh[wave][lane * 4 + 3] = st.acc.w;
    __syncthreads();
    float r = acc_sh[0][tid] + acc_sh[1][tid] + acc_sh[2][tid] + acc_sh[3][tid];
    r = (st.l > 0.f) ? r / st.l : 0.f;
    xcat[(size_t)b * K2 + D + tid] = r;
}

extern "C" void kernel_launch(void* const* d_in, const int* in_sizes, int n_in,
                              void* d_out, int out_size, void* d_ws, size_t ws_size,
                              hipStream_t stream) {
    const float* feat   = (const float*)d_in[0];
    const int*   segids = (const int*)d_in[1];
    const float* W_ih   = (const float*)d_in[2];
    const float* W_hh   = (const float*)d_in[3];
    const float* b_ih   = (const float*)d_in[4];
    const float* b_hh   = (const float*)d_in[5];
    const float* fc_w   = (const float*)d_in[6];
    const float* fc_b   = (const float*)d_in[7];
    float* out = (float*)d_out;
    int N = in_sizes[1];   // N_NODES

    float* Wc    = (float*)d_ws;                 // [G4, K2]
    float* bc    = Wc   + (size_t)G4 * K2;       // [G4]
    float* xcat  = bc   + G4;                    // [B, K2]  = [h | readout] = q_star
    float* cbuf  = xcat + (size_t)B * K2;        // [B, D]
    float* gates = cbuf + (size_t)B * D;         // [B, G4]
    int*   segs  = (int*)(gates + (size_t)B * G4); // [B+1]

    hipMemsetAsync(xcat, 0, (size_t)B * K2 * sizeof(float), stream);
    hipMemsetAsync(cbuf, 0, (size_t)B * D  * sizeof(float), stream);

    hipLaunchKernelGGL(prep_weights, dim3((G4 * K2 + 255) / 256), dim3(256), 0, stream,
                       W_ih, W_hh, b_ih, b_hh, Wc, bc);
    hipLaunchKernelGGL(seg_bounds, dim3((B + 1 + 255) / 256), dim3(256), 0, stream,
                       segids, segs, N);

    for (int it = 0; it < 6; ++it) {
        hipLaunchKernelGGL(gemm_nt, dim3(G4 / 64, B / 64), dim3(256), 0, stream,
                           xcat, Wc, bc, gates, B, G4, K2);
        hipLaunchKernelGGL(lstm_ep, dim3(B), dim3(256), 0, stream, gates, cbuf, xcat);
        hipLaunchKernelGGL(attn, dim3(B), dim3(256), 0, stream, feat, segs, xcat);
    }
    hipLaunchKernelGGL(gemm_nt, dim3(D / 64, B / 64), dim3(256), 0, stream,
                       xcat, fc_w, fc_b, out, B, D, K2);
}

// Round 4
// 1108.331 us; speedup vs baseline: 1.4084x; 1.1110x over previous
//
#include <hip/hip_runtime.h>

#define D   256    // HIDDEN
#define B   1024   // NUM_GRAPHS
#define K2  512    // 2*D
#define G4  1024   // 4*D

__device__ __forceinline__ float sigm(float x)   { return 1.f / (1.f + __expf(-x)); }
__device__ __forceinline__ float tanh_f(float x) { return 1.f - 2.f / (1.f + __expf(2.f * x)); }

// ---------------- weight prep: Wc = [W_ih[:,:D] + W_hh | W_ih[:,D:]], bc = b_ih + b_hh
__global__ void prep_weights(const float* __restrict__ W_ih, const float* __restrict__ W_hh,
                             const float* __restrict__ b_ih, const float* __restrict__ b_hh,
                             float* __restrict__ Wc, float* __restrict__ bc) {
    int idx = blockIdx.x * blockDim.x + threadIdx.x;
    if (idx < G4 * K2) {
        int j = idx >> 9;
        int k = idx & 511;
        float w = W_ih[idx];
        if (k < D) w += W_hh[j * D + k];
        Wc[idx] = w;
    }
    if (idx < G4) bc[idx] = b_ih[idx] + b_hh[idx];
}

// ---------------- segment bounds via binary search (segment_ids sorted)
__global__ void seg_bounds(const int* __restrict__ seg, int* __restrict__ out, int N) {
    int b = blockIdx.x * blockDim.x + threadIdx.x;
    if (b > B) return;
    if (b == B) { out[B] = N; return; }
    int lo = 0, hi = N;
    while (lo < hi) {
        int mid = (lo + hi) >> 1;
        if (seg[mid] < b) lo = mid + 1; else hi = mid;
    }
    out[b] = lo;
}

// ---------------- fp32 GEMM, K-split via blockIdx.z:
// Cp[z][M,N] = A[:, z*ksz : (z+1)*ksz] * Bm^T (+ bias if z==0)
// 64x64 tile, 4x4 microtile, register prefetch of next k-tile.
__global__ __launch_bounds__(256) void gemm_nt(const float* __restrict__ A,
                                               const float* __restrict__ Bm,
                                               const float* __restrict__ bias,
                                               float* __restrict__ Cp,
                                               int M, int N, int K, int ksz) {
    __shared__ float As[16][68];
    __shared__ float Bs[16][68];
    int tid = threadIdx.x;
    int tx = tid & 15, ty = tid >> 4;
    int m0 = blockIdx.y << 6, n0 = blockIdx.x << 6;
    int z = blockIdx.z;
    int klo = z * ksz;
    float* C = Cp + (size_t)z * M * N;
    int lr = tid >> 2;            // 0..63 tile row
    int lk = (tid & 3) << 2;      // 0,4,8,12
    const float* pa = A  + (size_t)(m0 + lr) * K + klo + lk;
    const float* pb = Bm + (size_t)(n0 + lr) * K + klo + lk;
    float4 a4 = *(const float4*)pa;
    float4 b4 = *(const float4*)pb;
    float acc[4][4] = {};
    for (int k0 = 0; k0 < ksz; k0 += 16) {
        As[lk + 0][lr] = a4.x; As[lk + 1][lr] = a4.y; As[lk + 2][lr] = a4.z; As[lk + 3][lr] = a4.w;
        Bs[lk + 0][lr] = b4.x; Bs[lk + 1][lr] = b4.y; Bs[lk + 2][lr] = b4.z; Bs[lk + 3][lr] = b4.w;
        __syncthreads();
        if (k0 + 16 < ksz) {      // issue next tile's loads before compute
            a4 = *(const float4*)(pa + k0 + 16);
            b4 = *(const float4*)(pb + k0 + 16);
        }
#pragma unroll
        for (int kk = 0; kk < 16; ++kk) {
            float a0 = As[kk][ty * 4 + 0], a1 = As[kk][ty * 4 + 1];
            float a2 = As[kk][ty * 4 + 2], a3 = As[kk][ty * 4 + 3];
            float b0 = Bs[kk][tx * 4 + 0], b1 = Bs[kk][tx * 4 + 1];
            float b2 = Bs[kk][tx * 4 + 2], b3 = Bs[kk][tx * 4 + 3];
            acc[0][0] += a0 * b0; acc[0][1] += a0 * b1; acc[0][2] += a0 * b2; acc[0][3] += a0 * b3;
            acc[1][0] += a1 * b0; acc[1][1] += a1 * b1; acc[1][2] += a1 * b2; acc[1][3] += a1 * b3;
            acc[2][0] += a2 * b0; acc[2][1] += a2 * b1; acc[2][2] += a2 * b2; acc[2][3] += a2 * b3;
            acc[3][0] += a3 * b0; acc[3][1] += a3 * b1; acc[3][2] += a3 * b2; acc[3][3] += a3 * b3;
        }
        __syncthreads();
    }
    int n = n0 + tx * 4;
    float bx = 0.f, by = 0.f, bz = 0.f, bw = 0.f;
    if (z == 0 && bias) { bx = bias[n]; by = bias[n + 1]; bz = bias[n + 2]; bw = bias[n + 3]; }
#pragma unroll
    for (int i = 0; i < 4; ++i) {
        int m = m0 + ty * 4 + i;
        float4 o;
        o.x = acc[i][0] + bx; o.y = acc[i][1] + by; o.z = acc[i][2] + bz; o.w = acc[i][3] + bw;
        *(float4*)(C + (size_t)m * N + n) = o;
    }
}

// ---------------- fused LSTM + split attention
// Grid = 4*B blocks (4 splits per segment), 256 thr = 4 waves.
// Prologue: LSTM cell for graph b (redundant x4; c double-buffered by parity).
// Loop: 64-node chunks in registers (wave w rows w*16..+15, lane l dims 4l..4l+3),
// LDS-transpose dot reduction, shuffle softmax, one barrier/chunk (esh/wsh ping-pong).
// Epilogue: partial (m, l, acc) written for the combine kernel.
__global__ __launch_bounds__(256) void attn(const float* __restrict__ feat,
                                            const int* __restrict__ segs,
                                            const float* __restrict__ gpart,
                                            const float* __restrict__ bc,
                                            float* __restrict__ cbuf,
                                            float* __restrict__ xcat,
                                            float* __restrict__ pm,
                                            float* __restrict__ pl,
                                            float* __restrict__ pacc,
                                            int it) {
    int blk = blockIdx.x, tid = threadIdx.x;
    int b = blk >> 2, sp = blk & 3;
    int wave = tid >> 6, lane = tid & 63;

    __shared__ float h_sh[D];
    __shared__ float pd[4][16][69];   // per-wave partial-dot transpose buffers
    __shared__ float esh[2][64];
    __shared__ float wsh[2][64];
    __shared__ float acc_sh[4][D];

    // ---- LSTM cell for graph b
    {
        int j = tid;
        float gi, gf, gg, go;
        if (it == 0) {
            gi = bc[j]; gf = bc[D + j]; gg = bc[2 * D + j]; go = bc[3 * D + j];
        } else {
            const float* g0 = gpart + (size_t)b * G4;
            const float* g1 = g0 + (size_t)B * G4;
            gi = g0[j]         + g1[j];
            gf = g0[D + j]     + g1[D + j];
            gg = g0[2 * D + j] + g1[2 * D + j];
            go = g0[3 * D + j] + g1[3 * D + j];
        }
        float cold = (it == 0) ? 0.f : cbuf[(size_t)(it & 1) * B * D + (size_t)b * D + j];
        float cn = sigm(gf) * cold + sigm(gi) * tanh_f(gg);
        float hn = sigm(go) * tanh_f(cn);
        cbuf[(size_t)((it & 1) ^ 1) * B * D + (size_t)b * D + j] = cn;  // same value x4 splits: benign
        xcat[(size_t)b * K2 + j] = hn;                                   // benign same-value race
        h_sh[j] = hn;
    }
    __syncthreads();
    float4 q4 = *(const float4*)&h_sh[lane * 4];

    int s0 = segs[b], e0 = segs[b + 1];
    int len = e0 - s0, span = (len + 3) >> 2;
    int s = s0 + sp * span;
    int e = min(s + span, e0);

    float m = -3.0e38f, l = 0.f;
    float4 acc = make_float4(0.f, 0.f, 0.f, 0.f);
    int par = 0;

    for (int base = s; base < e; base += 64, par ^= 1) {
        // ---- load 16 rows per wave (coalesced float4)
        float4 f[16];
#pragma unroll
        for (int t = 0; t < 16; ++t) {
            int n = base + wave * 16 + t;
            f[t] = (n < e) ? *(const float4*)(feat + (size_t)n * D + lane * 4)
                           : make_float4(0.f, 0.f, 0.f, 0.f);
        }
        // ---- partial dots -> LDS transpose -> 16-sum + 2-shfl reduce
#pragma unroll
        for (int t = 0; t < 16; ++t)
            pd[wave][t][lane] = f[t].x * q4.x + f[t].y * q4.y + f[t].z * q4.z + f[t].w * q4.w;
        int tt = lane & 15, sg = lane >> 4;
        float r = 0.f;
#pragma unroll
        for (int i = 0; i < 16; ++i) r += pd[wave][tt][sg * 16 + i];
        r += __shfl_xor(r, 16, 64);
        r += __shfl_xor(r, 32, 64);
        if (lane < 16) esh[par][wave * 16 + lane] = r;
        __syncthreads();
        // ---- softmax over the 64 chunk rows (lane l owns row l)
        float ev = (base + lane < e) ? esh[par][lane] : -3.0e38f;
        float cm = ev;
#pragma unroll
        for (int off = 32; off > 0; off >>= 1) cm = fmaxf(cm, __shfl_xor(cm, off, 64));
        float mc = fmaxf(m, cm);
        float wl = __expf(ev - mc);
        float ws = wl;
#pragma unroll
        for (int off = 32; off > 0; off >>= 1) ws += __shfl_xor(ws, off, 64);
        float sc = __expf(m - mc);
        l = l * sc + ws;
        m = mc;
        acc.x *= sc; acc.y *= sc; acc.z *= sc; acc.w *= sc;
        wsh[par][lane] = wl;          // all waves write identical values: benign
        // ---- weighted accumulate (weights via LDS broadcast reads)
#pragma unroll
        for (int t = 0; t < 16; ++t) {
            float w = wsh[par][wave * 16 + t];
            acc.x = fmaf(w, f[t].x, acc.x);
            acc.y = fmaf(w, f[t].y, acc.y);
            acc.z = fmaf(w, f[t].z, acc.z);
            acc.w = fmaf(w, f[t].w, acc.w);
        }
    }
    // ---- cross-wave reduce, write split partials
    acc_sh[wave][lane * 4 + 0] = acc.x;
    acc_sh[wave][lane * 4 + 1] = acc.y;
    acc_sh[wave][lane * 4 + 2] = acc.z;
    acc_sh[wave][lane * 4 + 3] = acc.w;
    __syncthreads();
    float r4 = acc_sh[0][tid] + acc_sh[1][tid] + acc_sh[2][tid] + acc_sh[3][tid];
    pacc[(size_t)blk * D + tid] = r4;
    if (tid == 0) { pm[blk] = m; pl[blk] = l; }
}

// ---------------- combine 4 split partials -> readout -> xcat[:, D:2D]
__global__ __launch_bounds__(256) void attn_combine(const float* __restrict__ pm,
                                                    const float* __restrict__ pl,
                                                    const float* __restrict__ pacc,
                                                    float* __restrict__ xcat) {
    int b = blockIdx.x, tid = threadIdx.x;
    float m0 = pm[4 * b], m1 = pm[4 * b + 1], m2 = pm[4 * b + 2], m3 = pm[4 * b + 3];
    float M = fmaxf(fmaxf(m0, m1), fmaxf(m2, m3));
    float w0 = __expf(m0 - M), w1 = __expf(m1 - M), w2 = __expf(m2 - M), w3 = __expf(m3 - M);
    float L = pl[4 * b] * w0 + pl[4 * b + 1] * w1 + pl[4 * b + 2] * w2 + pl[4 * b + 3] * w3;
    float R = pacc[(size_t)(4 * b + 0) * D + tid] * w0
            + pacc[(size_t)(4 * b + 1) * D + tid] * w1
            + pacc[(size_t)(4 * b + 2) * D + tid] * w2
            + pacc[(size_t)(4 * b + 3) * D + tid] * w3;
    xcat[(size_t)b * K2 + D + tid] = (L > 0.f) ? R / L : 0.f;
}

extern "C" void kernel_launch(void* const* d_in, const int* in_sizes, int n_in,
                              void* d_out, int out_size, void* d_ws, size_t ws_size,
                              hipStream_t stream) {
    const float* feat   = (const float*)d_in[0];
    const int*   segids = (const int*)d_in[1];
    const float* W_ih   = (const float*)d_in[2];
    const float* W_hh   = (const float*)d_in[3];
    const float* b_ih   = (const float*)d_in[4];
    const float* b_hh   = (const float*)d_in[5];
    const float* fc_w   = (const float*)d_in[6];
    const float* fc_b   = (const float*)d_in[7];
    float* out = (float*)d_out;
    int N = in_sizes[1];   // N_NODES

    // workspace carve-up (floats): ~18.9 MB total
    float* Wc    = (float*)d_ws;                   // [G4][K2]      524288
    float* bc    = Wc + (size_t)G4 * K2;           // [G4]          1024
    float* xcat  = bc + G4;                        // [B][K2]       524288
    float* cbuf  = xcat + (size_t)B * K2;          // [2][B][D]     524288
    float* gpart = cbuf + (size_t)2 * B * D;       // [2][B][G4]    2097152
    float* pm    = gpart + (size_t)2 * B * G4;     // [4B]          4096
    float* pl    = pm + 4 * B;                     // [4B]          4096
    float* pacc  = pl + 4 * B;                     // [4B][D]       1048576
    int*   segs  = (int*)(pacc + (size_t)4 * B * D); // [B+1]

    hipLaunchKernelGGL(prep_weights, dim3((G4 * K2 + 255) / 256), dim3(256), 0, stream,
                       W_ih, W_hh, b_ih, b_hh, Wc, bc);
    hipLaunchKernelGGL(seg_bounds, dim3((B + 1 + 255) / 256), dim3(256), 0, stream,
                       segids, segs, N);

    for (int it = 0; it < 6; ++it) {
        if (it > 0)   // it==0: q_star=0 -> gates = bc, handled in attn prologue
            hipLaunchKernelGGL(gemm_nt, dim3(G4 / 64, B / 64, 2), dim3(256), 0, stream,
                               xcat, Wc, bc, gpart, B, G4, K2, K2 / 2);
        hipLaunchKernelGGL(attn, dim3(4 * B), dim3(256), 0, stream,
                           feat, segs, gpart, bc, cbuf, xcat, pm, pl, pacc, it);
        hipLaunchKernelGGL(attn_combine, dim3(B), dim3(256), 0, stream, pm, pl, pacc, xcat);
    }
    hipLaunchKernelGGL(gemm_nt, dim3(D / 64, B / 64, 1), dim3(256), 0, stream,
                       xcat, fc_w, fc_b, out, B, D, K2, K2);
}